// Round 9
// baseline (47.592 us; speedup 1.0000x reference)
//
#include <hip/hip_runtime.h>

#define B 256
#define N 2048
#define P 2048
#define C 10
#define S_CHUNKS 16
#define PPB (P / S_CHUNKS)     // 128 pairs per block
#define NIT (PPB / 32)         // 4 iterations... (32 pairs per block-iter)
#define LN_EPS 1e-5f

typedef float v2f __attribute__((ext_vector_type(2)));

// ---- VOP3P packed fp32 (plain forms only -- proven R3/R4/R6/R7/R8) ---------
static __device__ __forceinline__ v2f pk_fma(v2f a, v2f b, v2f c) {
    v2f d;
    asm("v_pk_fma_f32 %0, %1, %2, %3" : "=v"(d) : "v"(a), "v"(b), "v"(c));
    return d;
}
static __device__ __forceinline__ v2f pk_add(v2f a, v2f b) {
    v2f d;
    asm("v_pk_add_f32 %0, %1, %2" : "=v"(d) : "v"(a), "v"(b));
    return d;
}

// ---- 16-lane all-reduce sum via DPP butterfly (proven R2..R8) --------------
static __device__ __forceinline__ float red16(float x) {
    x += __int_as_float(__builtin_amdgcn_update_dpp(0, __float_as_int(x), 0xB1,  0xF, 0xF, true));
    x += __int_as_float(__builtin_amdgcn_update_dpp(0, __float_as_int(x), 0x4E,  0xF, 0xF, true));
    x += __int_as_float(__builtin_amdgcn_update_dpp(0, __float_as_int(x), 0x141, 0xF, 0xF, true));
    x += __int_as_float(__builtin_amdgcn_update_dpp(0, __float_as_int(x), 0x140, 0xF, 0xF, true));
    return x;
}

// ---------------------------------------------------------------------------
// Kernel 1 (merged prep+triple, unchanged): every block redundantly reduces
// the 6 variance-quadratic scalars; block 0 writes the swizzled per-lane
// weight table; all blocks write T = rsqrt(var+eps) * (x0, x1, 1).
// ---------------------------------------------------------------------------
__global__ __launch_bounds__(256) void triple_kernel(
        const float* __restrict__ X,
        const float* __restrict__ W1, const float* __restrict__ b1,
        const float* __restrict__ gamma, const float* __restrict__ beta,
        float* __restrict__ wsw, float4* __restrict__ T) {
    const int t = threadIdx.x;
    __shared__ float r[6][128];
    __shared__ float sc[6];

    float w0 = 0.f, w1 = 0.f, bb = 0.f;
    if (t < 128) {
        w0 = W1[t]; w1 = W1[128 + t]; bb = b1[t];
        r[0][t] = w0; r[1][t] = w1; r[2][t] = bb;
    }
    __syncthreads();
    for (int s = 64; s > 0; s >>= 1) {
        if (t < s) { r[0][t] += r[0][t + s]; r[1][t] += r[1][t + s]; r[2][t] += r[2][t + s]; }
        __syncthreads();
    }
    const float m0 = r[0][0] * (1.f / 128.f);
    const float m1 = r[1][0] * (1.f / 128.f);
    const float mb = r[2][0] * (1.f / 128.f);
    __syncthreads();
    float c0 = 0.f, c1 = 0.f, cb = 0.f;
    if (t < 128) {
        c0 = w0 - m0; c1 = w1 - m1; cb = bb - mb;
        r[0][t] = c0 * c0; r[1][t] = c1 * c1; r[2][t] = cb * cb;
        r[3][t] = c0 * c1; r[4][t] = c0 * cb; r[5][t] = c1 * cb;
    }
    __syncthreads();
    for (int s = 64; s > 0; s >>= 1) {
        if (t < s) {
            #pragma unroll
            for (int q = 0; q < 6; ++q) r[q][t] += r[q][t + s];
        }
        __syncthreads();
    }
    if (t < 6) sc[t] = r[t][0] * (1.f / 128.f);
    __syncthreads();

    if (blockIdx.x == 0 && t < 128) {
        const float g = gamma[t];
        const int s_ = t & 15, half = (t >> 4) & 1, m = t >> 5;
        float* dst = wsw + s_ * 32 + m * 8;
        dst[0 + half] = g * c0;
        dst[2 + half] = g * c1;
        dst[4 + half] = g * cb;
        dst[6 + half] = beta[t];
    }

    const float S00 = sc[0], S11 = sc[1], Sbb = sc[2];
    const float S01 = sc[3], S0b = sc[4], S1b = sc[5];
    const int gid = blockIdx.x * 256 + t;       // 0 .. B*N-1
    const float2 x = ((const float2*)X)[gid];
    const float v = fmaf(x.x * x.x, S00, fmaf(x.y * x.y, S11, Sbb))
                  + 2.f * fmaf(x.x * x.y, S01, fmaf(x.x, S0b, x.y * S1b));
    const float rs = rsqrtf(v + LN_EPS);
    T[gid] = float4{rs * x.x, rs * x.y, rs, 0.f};
}

// ---------------------------------------------------------------------------
// Kernel 2 (R6 structure, oversubscribed grid): 256 threads, grid (B, 16).
// 16-lane group handles 2 pair-streams per iter; sublane s owns d = s+32m
// (lo) and d = s+32m+16 (hi). Idx + stream-A data prefetched 1 iter ahead.
// ---------------------------------------------------------------------------
__global__ __launch_bounds__(256) void pair_kernel(
        const float4* __restrict__ T,
        const int*    __restrict__ pairs,
        const float*  __restrict__ wsw,
        float* __restrict__ part) {
    const int b = blockIdx.x;
    const int chunk = blockIdx.y;
    const int tid = threadIdx.x;
    const int w = tid >> 6, l = tid & 63, g = l >> 4, s = l & 15;
    const int slot = w * 4 + g;      // 0..15

    // per-lane packed weights from swizzled table: 8x dwordx4
    const float4* Wl = (const float4*)(wsw + s * 32);
    v2f gw0[4], gw1[4], gbc[4], be2[4];
    #pragma unroll
    for (int m = 0; m < 4; ++m) {
        const float4 a = Wl[2 * m], c = Wl[2 * m + 1];
        gw0[m] = v2f{a.x, a.y}; gw1[m] = v2f{a.z, a.w};
        gbc[m] = v2f{c.x, c.y}; be2[m] = v2f{c.z, c.w};
    }
    const v2f neg1 = v2f{-1.f, -1.f};

    const float4* Tb  = T + (size_t)b * N;
    const int4*   pr4 = (const int4*)pairs;      // 2 pairs per int4
    const int i4base  = chunk * (PPB / 2);

    v2f acc[4];
    #pragma unroll
    for (int m = 0; m < 4; ++m) acc[m] = v2f{0.f, 0.f};

    auto proc = [&](const float4 ti, const float4 tj) {
        const v2f ai = v2f{ti.x, ti.x}, bi = v2f{ti.y, ti.y}, ci = v2f{ti.z, ti.z};
        const v2f aj = v2f{tj.x, tj.x}, bj = v2f{tj.y, tj.y}, cj = v2f{tj.z, tj.z};
        v2f uu[4], vv[4];
        v2f nu2 = v2f{0.f, 0.f}, nv2 = v2f{0.f, 0.f};
        #pragma unroll
        for (int m = 0; m < 4; ++m) {
            const v2f hi = pk_fma(ai, gw0[m], pk_fma(bi, gw1[m], pk_fma(ci, gbc[m], be2[m])));
            const v2f hj = pk_fma(aj, gw0[m], pk_fma(bj, gw1[m], pk_fma(cj, gbc[m], be2[m])));
            const v2f za = v2f{fmaxf(hi.x, 0.f), fmaxf(hi.y, 0.f)};
            const v2f zb = v2f{fmaxf(hj.x, 0.f), fmaxf(hj.y, 0.f)};
            const v2f u = pk_fma(zb, neg1, za);   // za - zb
            const v2f v = pk_add(za, zb);         // za + zb
            nu2 = pk_fma(u, u, nu2);
            nv2 = pk_fma(v, v, nv2);
            uu[m] = u; vv[m] = v;
        }
        const float nu = red16(nu2.x + nu2.y);
        const float nv = red16(nv2.x + nv2.y);
        const float ru = rsqrtf(fmaxf(nu, 1e-24f));
        const float rv = rsqrtf(fmaxf(nv, 1e-24f));
        const v2f ru2 = v2f{ru, ru}, rv2 = v2f{rv, rv};
        #pragma unroll
        for (int m = 0; m < 4; ++m)
            acc[m] = pk_fma(uu[m], ru2, pk_fma(vv[m], rv2, acc[m]));
    };

    // software pipeline: idx prefetched 1 iter; stream-A data prefetched
    int4 idx = pr4[i4base + slot];
    float4 tiA = Tb[idx.x], tjA = Tb[idx.y];

    for (int t = 0; t < NIT; ++t) {
        const float4 tiB = Tb[idx.z], tjB = Tb[idx.w];
        int4 nidx = idx;
        if (t + 1 < NIT) nidx = pr4[i4base + (t + 1) * 16 + slot];

        proc(tiA, tjA);                          // stream A (prefetched data)

        const float4 ntiA = Tb[nidx.x], ntjA = Tb[nidx.y];  // next A data

        proc(tiB, tjB);                          // stream B (loads hidden under A)

        idx = nidx; tiA = ntiA; tjA = ntjA;
    }

    // block reduce: 16 slots -> one 128-float partial (padded: conflict-free)
    __shared__ float red[16][8][17];
    #pragma unroll
    for (int m = 0; m < 4; ++m) {
        red[slot][2 * m    ][s] = acc[m].x;   // d = s + 32m
        red[slot][2 * m + 1][s] = acc[m].y;   // d = s + 32m + 16
    }
    __syncthreads();
    if (tid < 128) {
        const int ss = tid & 15, kk = tid >> 4;   // d = ss + 16*kk == tid
        float sum = 0.f;
        #pragma unroll
        for (int q = 0; q < 16; ++q) sum += red[q][kk][ss];
        part[((size_t)b * S_CHUNKS + chunk) * 128 + tid] = sum;
    }
}

// ---------------------------------------------------------------------------
// Kernel 3: reduce partials -> sdi, MLP head + mem logits.
// ---------------------------------------------------------------------------
__global__ __launch_bounds__(256) void head_kernel(
        const float* __restrict__ part,
        const float* __restrict__ Wm1, const float* __restrict__ bm1,
        const float* __restrict__ Wm2, const float* __restrict__ bm2,
        const float* __restrict__ mem,
        float* __restrict__ out_logits, float* __restrict__ out_sdi) {
    const int b = blockIdx.x;
    const int t = threadIdx.x;
    __shared__ float s[128];
    __shared__ float h[128];

    if (t < 128) {
        float sv = 0.f;
        #pragma unroll
        for (int k = 0; k < S_CHUNKS; ++k)
            sv += part[((size_t)b * S_CHUNKS + k) * 128 + t];
        sv *= (1.f / (2.f * P));
        s[t] = sv;
        out_sdi[(size_t)b * 128 + t] = sv;
    }
    __syncthreads();
    if (t < 128) {
        float a = bm1[t];
        for (int d = 0; d < 128; ++d) a = fmaf(s[d], Wm1[d * 128 + t], a);
        h[t] = fmaxf(a, 0.f);
    }
    __syncthreads();
    if (t < 16 * C) {                       // 160 threads: 16 lanes per class
        const int c = t >> 4, l = t & 15;
        float lg = 0.f;
        #pragma unroll
        for (int q = 0; q < 8; ++q) {
            const int d = l + 16 * q;
            lg = fmaf(s[d], mem[c * 128 + d], fmaf(h[d], Wm2[d * C + c], lg));
        }
        lg = red16(lg);
        if (l == 0) out_logits[(size_t)b * C + c] = lg + bm2[c];
    }
}

extern "C" void kernel_launch(void* const* d_in, const int* in_sizes, int n_in,
                              void* d_out, int out_size, void* d_ws, size_t ws_size,
                              hipStream_t stream) {
    const float* X     = (const float*)d_in[0];
    const int*   pairs = (const int*)  d_in[1];
    const float* W1    = (const float*)d_in[2];
    const float* b1    = (const float*)d_in[3];
    const float* gamma = (const float*)d_in[4];
    const float* beta  = (const float*)d_in[5];
    const float* Wm1   = (const float*)d_in[6];
    const float* bm1   = (const float*)d_in[7];
    const float* Wm2   = (const float*)d_in[8];
    const float* bm2   = (const float*)d_in[9];
    const float* mem   = (const float*)d_in[10];

    float* out = (float*)d_out;
    float* ws  = (float*)d_ws;
    float*  wsw  = ws;                           // 512 floats, swizzled weights
    float4* T    = (float4*)(ws + 512);          // B*N float4 (8 MB)
    float*  part = ws + 512 + (size_t)B * N * 4; // B*S_CHUNKS*128 floats (2 MB)

    triple_kernel<<<(B * N) / 256, 256, 0, stream>>>(X, W1, b1, gamma, beta, wsw, T);
    pair_kernel<<<dim3(B, S_CHUNKS), 256, 0, stream>>>(T, pairs, wsw, part);
    head_kernel<<<B, 256, 0, stream>>>(part, Wm1, bm1, Wm2, bm2, mem,
                                       out, out + (size_t)B * C);
}

// Round 11
// 37.169 us; speedup vs baseline: 1.2804x; 1.2804x over previous
//
#include <hip/hip_runtime.h>

#define B 256
#define N 2048
#define P 2048
#define C 10
#define S_CHUNKS 16
#define PPB (P / S_CHUNKS)     // 128 pairs per block
#define NIT (PPB / 32)         // 4 iterations; 32 pairs per block-iter
#define LN_EPS 1e-5f

typedef float v2f __attribute__((ext_vector_type(2)));
typedef _Float16 h2 __attribute__((ext_vector_type(2)));

// ---- f16 helpers: builtins with safe fallbacks (no hand-written asm) -------
static __device__ __forceinline__ float fdot2(h2 a, h2 b, float c) {
#if __has_builtin(__builtin_amdgcn_fdot2)
    return __builtin_amdgcn_fdot2(a, b, c, false);   // v_dot2_f32_f16
#else
    return (float)a.x * (float)b.x + (float)a.y * (float)b.y + c;
#endif
}
static __device__ __forceinline__ h2 h2fma(h2 a, h2 b, h2 c) {
#if __has_builtin(__builtin_elementwise_fma)
    return __builtin_elementwise_fma(a, b, c);        // v_pk_fma_f16
#else
    return a * b + c;
#endif
}
static __device__ __forceinline__ h2 h2relu(h2 x) {
#if __has_builtin(__builtin_elementwise_max)
    return __builtin_elementwise_max(x, h2{(_Float16)0.f, (_Float16)0.f});
#else
    h2 r;
    r.x = x.x > (_Float16)0.f ? x.x : (_Float16)0.f;
    r.y = x.y > (_Float16)0.f ? x.y : (_Float16)0.f;
    return r;
#endif
}
static __device__ __forceinline__ h2 pkrtz(float a, float b) {
#if __has_builtin(__builtin_amdgcn_cvt_pkrtz)
    return __builtin_bit_cast(h2, __builtin_amdgcn_cvt_pkrtz(a, b));  // v_cvt_pkrtz_f16_f32
#else
    return h2{(_Float16)a, (_Float16)b};
#endif
}
static __device__ __forceinline__ unsigned pk_rne(float a, float b) {
    return __builtin_bit_cast(unsigned, h2{(_Float16)a, (_Float16)b});
}

// ---- 16-lane all-reduce sum via DPP butterfly (proven R2..R9) --------------
static __device__ __forceinline__ float red16(float x) {
    x += __int_as_float(__builtin_amdgcn_update_dpp(0, __float_as_int(x), 0xB1,  0xF, 0xF, true));
    x += __int_as_float(__builtin_amdgcn_update_dpp(0, __float_as_int(x), 0x4E,  0xF, 0xF, true));
    x += __int_as_float(__builtin_amdgcn_update_dpp(0, __float_as_int(x), 0x141, 0xF, 0xF, true));
    x += __int_as_float(__builtin_amdgcn_update_dpp(0, __float_as_int(x), 0x140, 0xF, 0xF, true));
    return x;
}

// ---------------------------------------------------------------------------
// Kernel 1: every block redundantly reduces the 6 variance-quadratic scalars;
// block 0 writes the f16-packed per-sublane weight table; all blocks write
// the packed-f16 per-node triple T = {pk(rs*x0, rs*x1), pk(rs, 1)}.
// ---------------------------------------------------------------------------
__global__ __launch_bounds__(256) void triple_kernel(
        const float* __restrict__ X,
        const float* __restrict__ W1, const float* __restrict__ b1,
        const float* __restrict__ gamma, const float* __restrict__ beta,
        unsigned* __restrict__ wsw, uint2* __restrict__ T) {
    const int t = threadIdx.x;
    __shared__ float r[6][128];
    __shared__ float sc[6];

    float w0 = 0.f, w1 = 0.f, bb = 0.f;
    if (t < 128) {
        w0 = W1[t]; w1 = W1[128 + t]; bb = b1[t];
        r[0][t] = w0; r[1][t] = w1; r[2][t] = bb;
    }
    __syncthreads();
    for (int s = 64; s > 0; s >>= 1) {
        if (t < s) { r[0][t] += r[0][t + s]; r[1][t] += r[1][t + s]; r[2][t] += r[2][t + s]; }
        __syncthreads();
    }
    const float m0 = r[0][0] * (1.f / 128.f);
    const float m1 = r[1][0] * (1.f / 128.f);
    const float mb = r[2][0] * (1.f / 128.f);
    __syncthreads();
    float c0 = 0.f, c1 = 0.f, cb = 0.f;
    if (t < 128) {
        c0 = w0 - m0; c1 = w1 - m1; cb = bb - mb;
        r[0][t] = c0 * c0; r[1][t] = c1 * c1; r[2][t] = cb * cb;
        r[3][t] = c0 * c1; r[4][t] = c0 * cb; r[5][t] = c1 * cb;
    }
    __syncthreads();
    for (int s = 64; s > 0; s >>= 1) {
        if (t < s) {
            #pragma unroll
            for (int q = 0; q < 6; ++q) r[q][t] += r[q][t + s];
        }
        __syncthreads();
    }
    if (t < 6) sc[t] = r[t][0] * (1.f / 128.f);
    __syncthreads();

    // read scalars before r[] is reused
    const float S00 = sc[0], S11 = sc[1], Sbb = sc[2];
    const float S01 = sc[3], S0b = sc[4], S1b = sc[5];

    // stage gamma-folded weights for f16 packing
    if (t < 128) {
        const float g = gamma[t];
        r[0][t] = g * c0; r[1][t] = g * c1; r[2][t] = g * cb; r[3][t] = beta[t];
    }
    __syncthreads();
    // block 0: f16 weight table. sublane s, m: lanes pack d0=s+32m, d1=d0+16
    if (blockIdx.x == 0 && t < 16) {
        uint4* dst = (uint4*)wsw + t * 4;
        #pragma unroll
        for (int m = 0; m < 4; ++m) {
            const int d0 = t + 32 * m, d1 = d0 + 16;
            dst[m] = uint4{pk_rne(r[0][d0], r[0][d1]), pk_rne(r[1][d0], r[1][d1]),
                           pk_rne(r[2][d0], r[2][d1]), pk_rne(r[3][d0], r[3][d1])};
        }
    }

    const int gid = blockIdx.x * 256 + t;       // 0 .. B*N-1
    const float2 x = ((const float2*)X)[gid];
    const float v = fmaf(x.x * x.x, S00, fmaf(x.y * x.y, S11, Sbb))
                  + 2.f * fmaf(x.x * x.y, S01, fmaf(x.x, S0b, x.y * S1b));
    const float rs = rsqrtf(v + LN_EPS);
    T[gid] = uint2{pk_rne(rs * x.x, rs * x.y), pk_rne(rs, 1.f)};
}

// ---------------------------------------------------------------------------
// Kernel 2 (R9 structure, f16 m-loop): 256 threads, grid (B, 16).
// 16-lane group handles 2 pair-streams per iter; sublane s owns d = s+32m
// (lo half) and d = s+32m+16 (hi half) as packed f16 pairs.
// ---------------------------------------------------------------------------
__global__ __launch_bounds__(256) void pair_kernel(
        const uint2*    __restrict__ T,
        const int*      __restrict__ pairs,
        const unsigned* __restrict__ wsw,
        float* __restrict__ part) {
    const int b = blockIdx.x;
    const int chunk = blockIdx.y;
    const int tid = threadIdx.x;
    const int w = tid >> 6, l = tid & 63, g = l >> 4, s = l & 15;
    const int slot = w * 4 + g;      // 0..15

    // per-lane packed f16 weights: 4x dwordx4
    const uint4* Wl = (const uint4*)wsw + s * 4;
    h2 gw0[4], gw1[4], gbc[4], be2[4];
    #pragma unroll
    for (int m = 0; m < 4; ++m) {
        const uint4 wm = Wl[m];
        gw0[m] = __builtin_bit_cast(h2, wm.x);
        gw1[m] = __builtin_bit_cast(h2, wm.y);
        gbc[m] = __builtin_bit_cast(h2, wm.z);
        be2[m] = __builtin_bit_cast(h2, wm.w);
    }

    const uint2* Tb  = T + (size_t)b * N;
    const int4*  pr4 = (const int4*)pairs;      // 2 pairs per int4
    const int i4base = chunk * (PPB / 2);

    v2f acc[4];
    #pragma unroll
    for (int m = 0; m < 4; ++m) acc[m] = v2f{0.f, 0.f};

    auto proc = [&](const uint2 ti, const uint2 tj) {
        const h2 abi = __builtin_bit_cast(h2, ti.x), ci = __builtin_bit_cast(h2, ti.y);
        const h2 abj = __builtin_bit_cast(h2, tj.x), cj = __builtin_bit_cast(h2, tj.y);
        const h2 aai = h2{abi.x, abi.x}, bbi = h2{abi.y, abi.y}, cci = h2{ci.x, ci.x};
        const h2 aaj = h2{abj.x, abj.x}, bbj = h2{abj.y, abj.y}, ccj = h2{cj.x, cj.x};
        h2 uu[4], vv[4];
        float nu = 0.f, nv = 0.f;
        #pragma unroll
        for (int m = 0; m < 4; ++m) {
            const h2 hi = h2relu(h2fma(aai, gw0[m], h2fma(bbi, gw1[m], h2fma(cci, gbc[m], be2[m]))));
            const h2 hj = h2relu(h2fma(aaj, gw0[m], h2fma(bbj, gw1[m], h2fma(ccj, gbc[m], be2[m]))));
            const h2 u = hi - hj;
            const h2 v = hi + hj;
            nu = fdot2(u, u, nu);
            nv = fdot2(v, v, nv);
            uu[m] = u; vv[m] = v;
        }
        nu = red16(nu);
        nv = red16(nv);
        const float ru = rsqrtf(fmaxf(nu, 1e-24f));
        const float rv = rsqrtf(fmaxf(nv, 1e-24f));
        const h2 ruv = pkrtz(ru, rv);
        #pragma unroll
        for (int m = 0; m < 4; ++m) {
            acc[m].x = fdot2(h2{uu[m].x, vv[m].x}, ruv, acc[m].x);
            acc[m].y = fdot2(h2{uu[m].y, vv[m].y}, ruv, acc[m].y);
        }
    };

    // software pipeline: idx prefetched 1 iter; stream-A data prefetched
    int4 idx = pr4[i4base + slot];
    uint2 tiA = Tb[idx.x], tjA = Tb[idx.y];

    for (int t = 0; t < NIT; ++t) {
        const uint2 tiB = Tb[idx.z], tjB = Tb[idx.w];
        int4 nidx = idx;
        if (t + 1 < NIT) nidx = pr4[i4base + (t + 1) * 16 + slot];

        proc(tiA, tjA);                          // stream A (prefetched data)

        const uint2 ntiA = Tb[nidx.x], ntjA = Tb[nidx.y];  // next A data

        proc(tiB, tjB);                          // stream B (loads hidden under A)

        idx = nidx; tiA = ntiA; tjA = ntjA;
    }

    // block reduce: 16 slots -> one 128-float partial (padded: conflict-free)
    __shared__ float red[16][8][17];
    #pragma unroll
    for (int m = 0; m < 4; ++m) {
        red[slot][2 * m    ][s] = acc[m].x;   // d = s + 32m
        red[slot][2 * m + 1][s] = acc[m].y;   // d = s + 32m + 16
    }
    __syncthreads();
    if (tid < 128) {
        const int ss = tid & 15, kk = tid >> 4;   // d = ss + 16*kk == tid
        float sum = 0.f;
        #pragma unroll
        for (int q = 0; q < 16; ++q) sum += red[q][kk][ss];
        part[((size_t)b * S_CHUNKS + chunk) * 128 + tid] = sum;
    }
}

// ---------------------------------------------------------------------------
// Kernel 3: reduce partials -> sdi, MLP head + mem logits.
// ---------------------------------------------------------------------------
__global__ __launch_bounds__(256) void head_kernel(
        const float* __restrict__ part,
        const float* __restrict__ Wm1, const float* __restrict__ bm1,
        const float* __restrict__ Wm2, const float* __restrict__ bm2,
        const float* __restrict__ mem,
        float* __restrict__ out_logits, float* __restrict__ out_sdi) {
    const int b = blockIdx.x;
    const int t = threadIdx.x;
    __shared__ float s[128];
    __shared__ float h[128];

    if (t < 128) {
        float sv = 0.f;
        #pragma unroll
        for (int k = 0; k < S_CHUNKS; ++k)
            sv += part[((size_t)b * S_CHUNKS + k) * 128 + t];
        sv *= (1.f / (2.f * P));
        s[t] = sv;
        out_sdi[(size_t)b * 128 + t] = sv;
    }
    __syncthreads();
    if (t < 128) {
        float a = bm1[t];
        for (int d = 0; d < 128; ++d) a = fmaf(s[d], Wm1[d * 128 + t], a);
        h[t] = fmaxf(a, 0.f);
    }
    __syncthreads();
    if (t < 16 * C) {                       // 160 threads: 16 lanes per class
        const int c = t >> 4, l = t & 15;
        float lg = 0.f;
        #pragma unroll
        for (int q = 0; q < 8; ++q) {
            const int d = l + 16 * q;
            lg = fmaf(s[d], mem[c * 128 + d], fmaf(h[d], Wm2[d * C + c], lg));
        }
        lg = red16(lg);
        if (l == 0) out_logits[(size_t)b * C + c] = lg + bm2[c];
    }
}

extern "C" void kernel_launch(void* const* d_in, const int* in_sizes, int n_in,
                              void* d_out, int out_size, void* d_ws, size_t ws_size,
                              hipStream_t stream) {
    const float* X     = (const float*)d_in[0];
    const int*   pairs = (const int*)  d_in[1];
    const float* W1    = (const float*)d_in[2];
    const float* b1    = (const float*)d_in[3];
    const float* gamma = (const float*)d_in[4];
    const float* beta  = (const float*)d_in[5];
    const float* Wm1   = (const float*)d_in[6];
    const float* bm1   = (const float*)d_in[7];
    const float* Wm2   = (const float*)d_in[8];
    const float* bm2   = (const float*)d_in[9];
    const float* mem   = (const float*)d_in[10];

    float* out = (float*)d_out;
    float* ws  = (float*)d_ws;
    unsigned* wsw  = (unsigned*)ws;              // 256 B f16 weight table (pad 512 floats)
    uint2*    T    = (uint2*)(ws + 512);         // B*N uint2 (4 MB)
    float*    part = ws + 512 + (size_t)B * N * 2; // B*S_CHUNKS*128 floats (2 MB)

    triple_kernel<<<(B * N) / 256, 256, 0, stream>>>(X, W1, b1, gamma, beta, wsw, T);
    pair_kernel<<<dim3(B, S_CHUNKS), 256, 0, stream>>>(T, pairs, wsw, part);
    head_kernel<<<B, 256, 0, stream>>>(part, Wm1, bm1, Wm2, bm2, mem,
                                       out, out + (size_t)B * C);
}